// Round 4
// baseline (575.948 us; speedup 1.0000x reference)
//
#include <hip/hip_runtime.h>
#include <cmath>

#define D_IN 256
#define H_DIM 128
#define NUM_GRAPHS 1024
#define CHUNK 512
#define SUBT 64
#define NSUBT (CHUNK / SUBT)
#define MAXSEG 16
#define REC_F 768  // floats per record: ewsum[256], ssum[256], mx[256]

typedef __attribute__((ext_vector_type(8))) __bf16 bf16x8;
typedef __attribute__((ext_vector_type(4))) float f32x4;
typedef __attribute__((ext_vector_type(4))) unsigned short ushort4v;

__device__ inline float b2f(unsigned short u) {
    unsigned int v = ((unsigned int)u) << 16;
    return __builtin_bit_cast(float, v);
}

// ---------------------------------------------------------------------------
// Pack W1 (f32 [256][128]) into bf16 MFMA B-fragment order.
// B-frag for mfma_f32_16x16x32_bf16: lane l holds B[k][n], n = nt*16 + (l&15),
// k = ks*32 + (l>>4)*8 + i. packed[((nt*8+ks)*64 + l)*8 + i]
// ---------------------------------------------------------------------------
__global__ void pack_w1(const float* __restrict__ W1, ushort* __restrict__ packed) {
    int tid = blockIdx.x * 256 + threadIdx.x;
    if (tid >= 8 * 8 * 64) return;
    int nt = tid >> 9;
    int ks = (tid >> 6) & 7;
    int l = tid & 63;
    int col = nt * 16 + (l & 15);
    int kbase = ks * 32 + ((l >> 4) & 3) * 8;
#pragma unroll
    for (int i = 0; i < 8; ++i) {
        float v = W1[(size_t)(kbase + i) * H_DIM + col];
        __bf16 b = (__bf16)v;
        packed[(size_t)tid * 8 + i] = __builtin_bit_cast(unsigned short, b);
    }
}

// ---------------------------------------------------------------------------
// Fused kernel, per-wave-independent structure:
//  - wave w owns rows [t*64 + w*16, +16) of each tile: loads them (hoisted),
//    scores them via MFMA, keeps weights in registers (butterfly leaves sum in
//    all lanes), stages bf16 rows in a PRIVATE LDS slice, pools them masked.
//  - no barriers except block-wide segment flush (~2 per chunk).
// ---------------------------------------------------------------------------
__global__ __launch_bounds__(256, 3) void fused_kernel(
    const float* __restrict__ x, const ushort* __restrict__ w1p,
    const float* __restrict__ b1, const float* __restrict__ W2,
    const float* __restrict__ b2, const int* __restrict__ batch,
    float* __restrict__ recs, int2* __restrict__ hdr,
    float* __restrict__ zpart, int N) {
    int tid = threadIdx.x;
    int l = tid & 63;
    int w = tid >> 6;
    int r16 = l & 15;
    int kg = l >> 4;
    int blk = blockIdx.x;
    long long base = (long long)blk * CHUNK;
    int chunkN = (int)min((long long)CHUNK, (long long)N - base);

    __shared__ ushort sx[4][16 * D_IN];   // 32 KB, per-wave private slices
    __shared__ float red[4][3][256];      // 12 KB, flush staging
    __shared__ int sbatch[CHUNK];
    __shared__ int seglist[MAXSEG + 1];
    __shared__ int snseg;

    if (tid < MAXSEG) hdr[blk * MAXSEG + tid] = make_int2(-1, 0);

    for (int i = tid; i < chunkN; i += 256) sbatch[i] = batch[base + i];
    __syncthreads();

    // segment boundary scan (wave 0, ballot-compaction)
    if (tid < 64) {
        int nseg = 0;
        for (int t0 = 0; t0 < chunkN; t0 += 64) {
            int i = t0 + l;
            bool flag = (i < chunkN) && (i == 0 || sbatch[i] != sbatch[i - 1]);
            unsigned long long m = __ballot(flag);
            if (l == 0) {
                while (m) {
                    int b = __ffsll(m) - 1;
                    if (nseg < MAXSEG) seglist[nseg] = t0 + b;
                    nseg++;
                    m &= m - 1;
                }
            }
            nseg = __shfl(nseg, 0, 64);
        }
        if (l == 0) {
            if (nseg > MAXSEG) nseg = MAXSEG;
            snseg = nseg;
            seglist[nseg] = chunkN;
        }
    }
    __syncthreads();

    // hoisted epilogue weights
    float w2v[8], b1v[8];
#pragma unroll
    for (int nt = 0; nt < 8; ++nt) {
        int c = nt * 16 + r16;
        w2v[nt] = W2[c];
        b1v[nt] = b1[c];
    }
    float bb = b2[0];
    int nsegL = snseg;

    f32x4 asum = {0.f, 0.f, 0.f, 0.f};
    f32x4 ssum = {0.f, 0.f, 0.f, 0.f};
    f32x4 mx = {-INFINITY, -INFINITY, -INFINITY, -INFINITY};
    float zacc = 0.f;
    int curseg = 0;

    for (int t = 0; t < NSUBT; ++t) {
        int tbase = t * SUBT;
        if (tbase >= chunkN) break;  // uniform
        int tileEnd = min(tbase + SUBT, chunkN);

        // ---- SCORE: hoist 16 independent x loads, cvt, stage LDS, MFMA ----
        int wr0 = tbase + w * 16;  // this wave's first row (in chunk)
        long long arow = base + wr0 + r16;
        if (arow >= N) arow = N - 1;
        const float* xptr = x + arow * D_IN + kg * 8;

        f32x4 xv[16];
#pragma unroll
        for (int ks = 0; ks < 8; ++ks) {
            xv[2 * ks] = *(const f32x4*)(xptr + ks * 32);
            xv[2 * ks + 1] = *(const f32x4*)(xptr + ks * 32 + 4);
        }
        bf16x8 af[8];
#pragma unroll
        for (int ks = 0; ks < 8; ++ks) {
#pragma unroll
            for (int i = 0; i < 4; ++i) {
                af[ks][i] = (__bf16)xv[2 * ks][i];
                af[ks][i + 4] = (__bf16)xv[2 * ks + 1][i];
            }
            // stage row r16 cols [ks*32+kg*8, +8) into private slice (swizzled)
            unsigned a = ((unsigned)(r16 * 512 + ks * 64 + kg * 16)) ^ ((r16 & 7) << 4);
            *(bf16x8*)((char*)sx[w] + a) = af[ks];
        }
        f32x4 acc[8] = {};
#pragma unroll
        for (int ks = 0; ks < 8; ++ks) {
#pragma unroll
            for (int nt = 0; nt < 8; ++nt) {
                bf16x8 bfw = *(const bf16x8*)(w1p + ((size_t)(nt * 8 + ks) * 64 + l) * 8);
                acc[nt] = __builtin_amdgcn_mfma_f32_16x16x32_bf16(af[ks], bfw, acc[nt], 0, 0, 0);
            }
        }
        // epilogue: butterfly leaves row-sum in ALL 16 lanes of the group
        float e[4];
#pragma unroll
        for (int reg = 0; reg < 4; ++reg) {
            float p = 0.f;
#pragma unroll
            for (int nt = 0; nt < 8; ++nt) {
                float h = acc[nt][reg] + b1v[nt];
                p += fmaxf(h, 0.f) * w2v[nt];
            }
            p += __shfl_xor(p, 1, 64);
            p += __shfl_xor(p, 2, 64);
            p += __shfl_xor(p, 4, 64);
            p += __shfl_xor(p, 8, 64);
            int rowc = wr0 + kg * 4 + reg;
            e[reg] = (rowc < chunkN) ? __expf(p + bb) : 0.f;
            zacc += e[reg];  // each row counted 16x; divide by 16 at end (exact)
        }

        // ---- POOL: fixed-trip masked runs over this wave's 16 rows ----
        while (true) {  // uniform control (seglist/tileEnd shared)
            int sStart = seglist[curseg];
            int sEnd = seglist[curseg + 1];
            int runEnd = min(sEnd, tileEnd);
#pragma unroll
            for (int j = 0; j < 16; ++j) {
                int i = tbase + w * 16 + j;
                float wj = __shfl(e[j & 3], (j >> 2) << 4, 64);
                bool in = (i >= sStart) && (i < runEnd);
                unsigned a = ((unsigned)(j * 512 + l * 8)) ^ ((j & 7) << 4);
                ushort4v hv = *(const ushort4v*)((char*)sx[w] + a);
                float wje = in ? wj : 0.f;
#pragma unroll
                for (int c = 0; c < 4; ++c) {
                    float v = b2f(hv[c]);
                    asum[c] += v * wje;
                    ssum[c] += in ? v : 0.f;
                    mx[c] = fmaxf(mx[c], in ? v : -INFINITY);
                }
            }
            if (runEnd == sEnd && curseg < nsegL) {
                // ---- FLUSH (block-uniform point) ----
                *(f32x4*)&red[w][0][l * 4] = asum;
                *(f32x4*)&red[w][1][l * 4] = ssum;
                *(f32x4*)&red[w][2][l * 4] = mx;
                __syncthreads();
                {
                    float aa = red[0][0][tid] + red[1][0][tid] +
                               red[2][0][tid] + red[3][0][tid];
                    float s2 = red[0][1][tid] + red[1][1][tid] +
                               red[2][1][tid] + red[3][1][tid];
                    float m2 = fmaxf(fmaxf(red[0][2][tid], red[1][2][tid]),
                                     fmaxf(red[2][2][tid], red[3][2][tid]));
                    float* rb = recs + (size_t)(blk * MAXSEG + curseg) * REC_F;
                    rb[tid] = aa;
                    rb[256 + tid] = s2;
                    rb[512 + tid] = m2;
                }
                if (tid == 0)
                    hdr[blk * MAXSEG + curseg] =
                        make_int2(sbatch[sStart], sEnd - sStart);
                __syncthreads();
#pragma unroll
                for (int c = 0; c < 4; ++c) {
                    asum[c] = 0.f;
                    ssum[c] = 0.f;
                    mx[c] = -INFINITY;
                }
                curseg++;
                if (runEnd >= tileEnd) break;
            } else {
                break;
            }
        }
    }

    // per-wave z partial (each row was added 16x; /16 is exact)
    zacc += __shfl_xor(zacc, 1, 64);
    zacc += __shfl_xor(zacc, 2, 64);
    zacc += __shfl_xor(zacc, 4, 64);
    zacc += __shfl_xor(zacc, 8, 64);
    zacc += __shfl_xor(zacc, 16, 64);
    zacc += __shfl_xor(zacc, 32, 64);
    if (l == 0) zpart[blk * 4 + w] = zacc * 0.0625f;
}

// ---------------------------------------------------------------------------
__device__ inline int lower_bound_i(const int* __restrict__ arr, int n, int val) {
    int lo = 0, hi = n;
    while (lo < hi) {
        int mid = (lo + hi) >> 1;
        if (arr[mid] < val) lo = mid + 1; else hi = mid;
    }
    return lo;
}

// One block per graph: merge partial records, normalize by Z, write output.
__global__ __launch_bounds__(256) void combine_kernel(
    const float* __restrict__ recs, const int2* __restrict__ hdr,
    const float* __restrict__ zpart, int nblk,
    const int* __restrict__ batch, int N, float* __restrict__ out) {
    int g = blockIdx.x;
    int tid = threadIdx.x;

    __shared__ float szr[256];
    float zs = 0.f;
    for (int i = tid; i < nblk * 4; i += 256) zs += zpart[i];
    szr[tid] = zs;
    __syncthreads();
    for (int off = 128; off > 0; off >>= 1) {
        if (tid < off) szr[tid] += szr[tid + off];
        __syncthreads();
    }
    float invZ = 1.f / szr[0];

    __shared__ int sb[2];
    if (tid < 2) sb[tid] = lower_bound_i(batch, N, g + tid);
    __syncthreads();
    int start = sb[0], end = sb[1];

    float ew = 0.f, ss = 0.f, mxv = -INFINITY;
    int cnt = 0;
    if (end > start) {
        int b0 = start / CHUNK, b1 = (end - 1) / CHUNK;
        for (int b = b0; b <= b1; ++b) {
            for (int si = 0; si < MAXSEG; ++si) {
                int2 h = hdr[b * MAXSEG + si];
                if (h.x == g) {
                    const float* rb = recs + (size_t)(b * MAXSEG + si) * REC_F;
                    ew += rb[tid];
                    ss += rb[256 + tid];
                    mxv = fmaxf(mxv, rb[512 + tid]);
                    cnt += h.y;
                }
            }
        }
    }
    size_t ob = (size_t)g * (3 * D_IN);
    out[ob + tid] = ew * invZ;
    out[ob + D_IN + tid] = (cnt > 0) ? mxv : 0.f;
    out[ob + 2 * D_IN + tid] = ss / (float)max(cnt, 1);
}

// ---------------------------------------------------------------------------
extern "C" void kernel_launch(void* const* d_in, const int* in_sizes, int n_in,
                              void* d_out, int out_size, void* d_ws, size_t ws_size,
                              hipStream_t stream) {
    const float* x = (const float*)d_in[0];
    const float* W1 = (const float*)d_in[1];
    const float* b1 = (const float*)d_in[2];
    const float* W2 = (const float*)d_in[3];
    const float* b2 = (const float*)d_in[4];
    const int* batch = (const int*)d_in[5];
    int N = in_sizes[0] / D_IN;
    float* out = (float*)d_out;
    int NB = (N + CHUNK - 1) / CHUNK;

    char* ws = (char*)d_ws;
    size_t off = 0;
    ushort* w1p = (ushort*)(ws + off);
    off += 8 * 8 * 64 * 8 * sizeof(ushort);  // 64 KB
    off = (off + 255) & ~(size_t)255;
    float* recs = (float*)(ws + off);
    off += (size_t)NB * MAXSEG * REC_F * sizeof(float);  // ~48 MB
    off = (off + 255) & ~(size_t)255;
    int2* hdr = (int2*)(ws + off);
    off += (size_t)NB * MAXSEG * sizeof(int2);
    off = (off + 255) & ~(size_t)255;
    float* zpart = (float*)(ws + off);
    off += (size_t)NB * 4 * sizeof(float);

    pack_w1<<<16, 256, 0, stream>>>(W1, w1p);
    fused_kernel<<<NB, 256, 0, stream>>>(x, w1p, b1, W2, b2, batch,
                                         recs, hdr, zpart, N);
    combine_kernel<<<NUM_GRAPHS, 256, 0, stream>>>(recs, hdr, zpart, NB,
                                                   batch, N, out);
}

// Round 5
// 275.302 us; speedup vs baseline: 2.0921x; 2.0921x over previous
//
#include <hip/hip_runtime.h>
#include <cmath>

#define D_IN 256
#define H_DIM 128
#define NUM_GRAPHS 1024
#define CHUNK 64
#define MAXSEG 16
#define REC_F 768  // floats per record: ewsum[256], ssum[256], mx[256]

typedef __attribute__((ext_vector_type(8))) __bf16 bf16x8;
typedef __attribute__((ext_vector_type(4))) float f32x4;

// ---------------------------------------------------------------------------
// Pack W1 (f32 [256][128]) into bf16 MFMA B-fragment order.
// B-frag for mfma_f32_16x16x32_bf16: lane l holds B[k][n], n = nt*16 + (l&15),
// k = ks*32 + (l>>4)*8 + i. packed[((nt*8+ks)*64 + l)*8 + i]
// ---------------------------------------------------------------------------
__global__ void pack_w1(const float* __restrict__ W1, ushort* __restrict__ packed) {
    int tid = blockIdx.x * 256 + threadIdx.x;
    if (tid >= 8 * 8 * 64) return;
    int nt = tid >> 9;
    int ks = (tid >> 6) & 7;
    int l = tid & 63;
    int col = nt * 16 + (l & 15);
    int kbase = ks * 32 + ((l >> 4) & 3) * 8;
#pragma unroll
    for (int i = 0; i < 8; ++i) {
        float v = W1[(size_t)(kbase + i) * H_DIM + col];
        __bf16 b = (__bf16)v;
        packed[(size_t)tid * 8 + i] = __builtin_bit_cast(unsigned short, b);
    }
}

// ---------------------------------------------------------------------------
// Fused kernel: one 64-row tile per block (7813 blocks -> 30/CU).
// Wave w owns rows [w*16, w*16+16): hoisted f32 loads -> bf16 MFMA scores ->
// weights stay in-wave -> pool by re-reading global (L1/L2-hot) at f32.
// Barriers only for segment scan + per-segment flush (~3 total).
// ---------------------------------------------------------------------------
__global__ __launch_bounds__(256) void fused_kernel(
    const float* __restrict__ x, const ushort* __restrict__ w1p,
    const float* __restrict__ b1, const float* __restrict__ W2,
    const float* __restrict__ b2, const int* __restrict__ batch,
    float* __restrict__ recs, int2* __restrict__ hdr,
    float* __restrict__ zpart, int N) {
    int tid = threadIdx.x;
    int l = tid & 63;
    int w = tid >> 6;
    int r16 = l & 15;
    int kg = l >> 4;
    int blk = blockIdx.x;
    long long base = (long long)blk * CHUNK;
    int chunkN = (int)min((long long)CHUNK, (long long)N - base);

    __shared__ int sbatch[CHUNK];
    __shared__ int seglist[MAXSEG + 1];
    __shared__ int snseg;
    __shared__ float red[4][3][256];  // 12 KB flush staging

    if (tid < MAXSEG) hdr[blk * MAXSEG + tid] = make_int2(-1, 0);
    if (tid < chunkN) sbatch[tid] = batch[base + tid];
    __syncthreads();

    // segment boundary scan: one ballot over the 64 rows (wave 0)
    if (tid < 64) {
        bool flag = (l < chunkN) && (l == 0 || sbatch[l] != sbatch[l - 1]);
        unsigned long long m = __ballot(flag);
        if (l == 0) {
            int nseg = 0;
            while (m) {
                int b = __ffsll(m) - 1;
                if (nseg < MAXSEG) seglist[nseg] = b;
                nseg++;
                m &= m - 1;
            }
            if (nseg > MAXSEG) nseg = MAXSEG;
            snseg = nseg;
            seglist[nseg] = chunkN;
        }
    }
    __syncthreads();

    // hoisted epilogue weights
    float w2v[8], b1v[8];
#pragma unroll
    for (int nt = 0; nt < 8; ++nt) {
        int c = nt * 16 + r16;
        w2v[nt] = W2[c];
        b1v[nt] = b1[c];
    }
    float bb = b2[0];
    int nseg = snseg;

    // ---- SCORE: 16 hoisted independent x loads -> cvt -> MFMA ----
    int wr0 = w * 16;  // wave's first row within chunk
    long long arow = base + wr0 + r16;
    if (arow >= N) arow = N - 1;
    const float* xptr = x + arow * D_IN + kg * 8;

    f32x4 xv[16];
#pragma unroll
    for (int ks = 0; ks < 8; ++ks) {
        xv[2 * ks] = *(const f32x4*)(xptr + ks * 32);
        xv[2 * ks + 1] = *(const f32x4*)(xptr + ks * 32 + 4);
    }
    bf16x8 af[8];
#pragma unroll
    for (int ks = 0; ks < 8; ++ks) {
#pragma unroll
        for (int i = 0; i < 4; ++i) {
            af[ks][i] = (__bf16)xv[2 * ks][i];
            af[ks][i + 4] = (__bf16)xv[2 * ks + 1][i];
        }
    }
    f32x4 acc[8] = {};
#pragma unroll
    for (int ks = 0; ks < 8; ++ks) {
#pragma unroll
        for (int nt = 0; nt < 8; ++nt) {
            bf16x8 bfw = *(const bf16x8*)(w1p + ((size_t)(nt * 8 + ks) * 64 + l) * 8);
            acc[nt] = __builtin_amdgcn_mfma_f32_16x16x32_bf16(af[ks], bfw, acc[nt], 0, 0, 0);
        }
    }
    // epilogue: butterfly leaves row score in all 16 lanes of each kg group
    float e[4];
    float zacc = 0.f;
#pragma unroll
    for (int reg = 0; reg < 4; ++reg) {
        float p = 0.f;
#pragma unroll
        for (int nt = 0; nt < 8; ++nt) {
            float h = acc[nt][reg] + b1v[nt];
            p += fmaxf(h, 0.f) * w2v[nt];
        }
        p += __shfl_xor(p, 1, 64);
        p += __shfl_xor(p, 2, 64);
        p += __shfl_xor(p, 4, 64);
        p += __shfl_xor(p, 8, 64);
        int rowc = wr0 + kg * 4 + reg;
        e[reg] = (rowc < chunkN) ? __expf(p + bb) : 0.f;
        zacc += e[reg];  // replicated 16x per row; /16 at the end (exact)
    }

    // ---- POOL + FLUSH per segment run (uniform loop) ----
    f32x4 asum = {0.f, 0.f, 0.f, 0.f};
    f32x4 ssum = {0.f, 0.f, 0.f, 0.f};
    f32x4 mx = {-INFINITY, -INFINITY, -INFINITY, -INFINITY};

    for (int sg = 0; sg < nseg; ++sg) {
        int sStart = seglist[sg];
        int sEnd = seglist[sg + 1];
#pragma unroll
        for (int j = 0; j < 16; ++j) {
            int i = wr0 + j;
            float wj = __shfl(e[j & 3], (j >> 2) << 4, 64);
            bool in = (i >= sStart) && (i < sEnd);
            long long grow = base + i;
            if (grow >= N) grow = N - 1;
            f32x4 v = *(const f32x4*)(x + grow * D_IN + l * 4);
            float wje = in ? wj : 0.f;
#pragma unroll
            for (int c = 0; c < 4; ++c) {
                asum[c] += v[c] * wje;
                ssum[c] += in ? v[c] : 0.f;
                mx[c] = fmaxf(mx[c], in ? v[c] : -INFINITY);
            }
        }
        // flush (block-uniform): reduce 4 waves via LDS, write record
        *(f32x4*)&red[w][0][l * 4] = asum;
        *(f32x4*)&red[w][1][l * 4] = ssum;
        *(f32x4*)&red[w][2][l * 4] = mx;
        __syncthreads();
        {
            float aa = red[0][0][tid] + red[1][0][tid] +
                       red[2][0][tid] + red[3][0][tid];
            float s2 = red[0][1][tid] + red[1][1][tid] +
                       red[2][1][tid] + red[3][1][tid];
            float m2 = fmaxf(fmaxf(red[0][2][tid], red[1][2][tid]),
                             fmaxf(red[2][2][tid], red[3][2][tid]));
            float* rb = recs + (size_t)(blk * MAXSEG + sg) * REC_F;
            rb[tid] = aa;
            rb[256 + tid] = s2;
            rb[512 + tid] = m2;
        }
        if (tid == 0)
            hdr[blk * MAXSEG + sg] = make_int2(sbatch[sStart], sEnd - sStart);
        __syncthreads();
#pragma unroll
        for (int c = 0; c < 4; ++c) {
            asum[c] = 0.f;
            ssum[c] = 0.f;
            mx[c] = -INFINITY;
        }
    }

    // per-wave z partial (each row counted 16x; /16 exact)
    zacc += __shfl_xor(zacc, 1, 64);
    zacc += __shfl_xor(zacc, 2, 64);
    zacc += __shfl_xor(zacc, 4, 64);
    zacc += __shfl_xor(zacc, 8, 64);
    zacc += __shfl_xor(zacc, 16, 64);
    zacc += __shfl_xor(zacc, 32, 64);
    if (l == 0) zpart[blk * 4 + w] = zacc * 0.0625f;
}

// ---------------------------------------------------------------------------
// Reduce all z partials to a single 1/Z.
// ---------------------------------------------------------------------------
__global__ __launch_bounds__(256) void zreduce_kernel(
    const float* __restrict__ zpart, int n, float* __restrict__ MZ) {
    int tid = threadIdx.x;
    float z = 0.f;
    for (int i = tid; i < n; i += 256) z += zpart[i];
    __shared__ float sz[256];
    sz[tid] = z;
    __syncthreads();
    for (int off = 128; off > 0; off >>= 1) {
        if (tid < off) sz[tid] += sz[tid + off];
        __syncthreads();
    }
    if (tid == 0) MZ[0] = 1.f / sz[0];
}

// ---------------------------------------------------------------------------
__device__ inline int lower_bound_i(const int* __restrict__ arr, int n, int val) {
    int lo = 0, hi = n;
    while (lo < hi) {
        int mid = (lo + hi) >> 1;
        if (arr[mid] < val) lo = mid + 1; else hi = mid;
    }
    return lo;
}

// One block per graph: merge partial records, normalize by Z, write output.
__global__ __launch_bounds__(256) void combine_kernel(
    const float* __restrict__ recs, const int2* __restrict__ hdr,
    const float* __restrict__ MZ,
    const int* __restrict__ batch, int N, float* __restrict__ out) {
    int g = blockIdx.x;
    int tid = threadIdx.x;
    float invZ = MZ[0];

    __shared__ int sb[2];
    if (tid < 2) sb[tid] = lower_bound_i(batch, N, g + tid);
    __syncthreads();
    int start = sb[0], end = sb[1];

    float ew = 0.f, ss = 0.f, mxv = -INFINITY;
    int cnt = 0;
    if (end > start) {
        int b0 = start / CHUNK, b1 = (end - 1) / CHUNK;
        for (int b = b0; b <= b1; ++b) {
            for (int si = 0; si < MAXSEG; ++si) {
                int2 h = hdr[b * MAXSEG + si];
                if (h.x == g) {
                    const float* rb = recs + (size_t)(b * MAXSEG + si) * REC_F;
                    ew += rb[tid];
                    ss += rb[256 + tid];
                    mxv = fmaxf(mxv, rb[512 + tid]);
                    cnt += h.y;
                }
            }
        }
    }
    size_t ob = (size_t)g * (3 * D_IN);
    out[ob + tid] = ew * invZ;
    out[ob + D_IN + tid] = (cnt > 0) ? mxv : 0.f;
    out[ob + 2 * D_IN + tid] = ss / (float)max(cnt, 1);
}

// ---------------------------------------------------------------------------
extern "C" void kernel_launch(void* const* d_in, const int* in_sizes, int n_in,
                              void* d_out, int out_size, void* d_ws, size_t ws_size,
                              hipStream_t stream) {
    const float* x = (const float*)d_in[0];
    const float* W1 = (const float*)d_in[1];
    const float* b1 = (const float*)d_in[2];
    const float* W2 = (const float*)d_in[3];
    const float* b2 = (const float*)d_in[4];
    const int* batch = (const int*)d_in[5];
    int N = in_sizes[0] / D_IN;
    float* out = (float*)d_out;
    int NB = (N + CHUNK - 1) / CHUNK;

    char* ws = (char*)d_ws;
    size_t off = 0;
    ushort* w1p = (ushort*)(ws + off);
    off += 8 * 8 * 64 * 8 * sizeof(ushort);  // 64 KB
    off = (off + 255) & ~(size_t)255;
    float* recs = (float*)(ws + off);
    off += (size_t)NB * MAXSEG * REC_F * sizeof(float);  // ~384 MB
    off = (off + 255) & ~(size_t)255;
    int2* hdr = (int2*)(ws + off);
    off += (size_t)NB * MAXSEG * sizeof(int2);  // ~1 MB
    off = (off + 255) & ~(size_t)255;
    float* zpart = (float*)(ws + off);
    off += (size_t)NB * 4 * sizeof(float);
    off = (off + 255) & ~(size_t)255;
    float* MZ = (float*)(ws + off);
    off += 256;

    pack_w1<<<16, 256, 0, stream>>>(W1, w1p);
    fused_kernel<<<NB, 256, 0, stream>>>(x, w1p, b1, W2, b2, batch,
                                         recs, hdr, zpart, N);
    zreduce_kernel<<<1, 256, 0, stream>>>(zpart, NB * 4, MZ);
    combine_kernel<<<NUM_GRAPHS, 256, 0, stream>>>(recs, hdr, MZ, batch, N, out);
}